// Round 14
// baseline (182.332 us; speedup 1.0000x reference)
//
#include <hip/hip_runtime.h>
#include <math.h>

// Problem constants (reference: B=4, N=8192, points are [B,N,3] fp32)
#define BATCH 4
#define NPTS 8192
#define BN (BATCH * NPTS)
#define NZB 16                 // 4 searches x 4 batches
#define QK 8                   // queries per lane in the scan
#define QBLK (256 * QK)        // 2048 queries per scan block
#define SUBT 64                // provenance subtile (rescan covers this many)

// Workspace: [0] double acc | [8] uint ticket | [64] int idx_all[NZB*NPTS]
//            [64+512K] float part_d[SPL][NZB*NPTS]
//            [after]   u8    part_t[SPL][NZB*NPTS]  (global subtile id)
// SPL=16 preferred: halves ws to ~10.8MB (harness re-poisons ws every timed
// launch — suspected component of the fixed ~95us "rest") while keeping scan
// occupancy identical (1024 blocks = exactly 4 blocks/CU resident).

__device__ __forceinline__ void pick_ab(int z, const float* pw, const float* pp,
                                        const float* tw, const float* tp,
                                        const float** qa, const float** cb) {
  if (z == 0)      { *qa = pw; *cb = pp; }
  else if (z == 1) { *qa = pp; *cb = pw; }
  else if (z == 2) { *qa = tw; *cb = tp; }
  else             { *qa = tp; *cb = tw; }
}

// ---------------------------------------------------------------------------
// Pass 1 (proven scalar form, ~85us): min-distance scan + subtile provenance.
// Scan formulations measured: scalar 85.5 / QK16 87 / MFMA16 98.5 /
// MFMA32 94.6 / pk_fma 86.6 — structural ~85us floor for this pattern
// (R13 proved it is NOT VALU-issue-bound: halving instrs changed nothing).
// ---------------------------------------------------------------------------
template <int SPL>
__global__ __launch_bounds__(256, 4) void nn_partial_kernel(
    const float* __restrict__ pw, const float* __restrict__ pp,
    const float* __restrict__ tw, const float* __restrict__ tp,
    float* __restrict__ part_d, unsigned char* __restrict__ part_t) {
  constexpr int SLICE = NPTS / SPL;
  constexpr int NSUB = SLICE / SUBT;
  __shared__ float4 sh[SLICE];

  const int zb = blockIdx.z;
  const int z = zb >> 2;
  const int b = zb & 3;
  const float* qa;
  const float* cb;
  pick_ab(z, pw, pp, tw, tp, &qa, &cb);

  const int tid = threadIdx.x;
  const int cslice = blockIdx.y * SLICE;
  const float* cbb = cb + (size_t)b * NPTS * 3;

  // Stage slice as (x,y,z,||b||^2); formulas must match rescan exactly.
  for (int m = tid; m < SLICE; m += 256) {
    const float* c = cbb + (size_t)(cslice + m) * 3;
    const float bx = c[0], by = c[1], bz = c[2];
    sh[m] = make_float4(bx, by, bz, fmaf(bx, bx, fmaf(by, by, bz * bz)));
  }
  __syncthreads();

  const int qbase = blockIdx.x * QBLK;
  float qx[QK], qy[QK], qz[QK], dmin[QK];
  int tile[QK];
  #pragma unroll
  for (int k = 0; k < QK; ++k) {
    const int n = qbase + tid + k * 256;
    const float* q = qa + ((size_t)b * NPTS + n) * 3;
    qx[k] = -2.0f * q[0];
    qy[k] = -2.0f * q[1];
    qz[k] = -2.0f * q[2];
    dmin[k] = INFINITY;
    tile[k] = 0;
  }

  for (int sub = 0; sub < NSUB; ++sub) {
    float pre[QK];
    #pragma unroll
    for (int k = 0; k < QK; ++k) pre[k] = dmin[k];

    const int cb0 = sub * SUBT;
    #pragma unroll 2
    for (int p = 0; p < SUBT / 2; ++p) {
      const float4 c0 = sh[cb0 + 2 * p];
      const float4 c1 = sh[cb0 + 2 * p + 1];
      float t0[QK], t1[QK];
      #pragma unroll
      for (int k = 0; k < QK; ++k)
        t0[k] = fmaf(qx[k], c0.x, fmaf(qy[k], c0.y, fmaf(qz[k], c0.z, c0.w)));
      #pragma unroll
      for (int k = 0; k < QK; ++k)
        t1[k] = fmaf(qx[k], c1.x, fmaf(qy[k], c1.y, fmaf(qz[k], c1.z, c1.w)));
      #pragma unroll
      for (int k = 0; k < QK; ++k)
        dmin[k] = fminf(fminf(t0[k], t1[k]), dmin[k]);   // v_min3_f32
    }
    const int g = blockIdx.y * NSUB + sub;   // global subtile id
    #pragma unroll
    for (int k = 0; k < QK; ++k)
      tile[k] = (dmin[k] < pre[k]) ? g : tile[k];  // strict <: first-min kept
  }

  #pragma unroll
  for (int k = 0; k < QK; ++k) {
    const int n = qbase + tid + k * 256;
    const size_t o = (size_t)blockIdx.y * (NZB * NPTS) + (size_t)zb * NPTS + n;
    part_d[o] = dmin[k];
    part_t[o] = (unsigned char)tile[k];
  }
}

// ---------------------------------------------------------------------------
// Pass 2 (proven R8 shape): fused merge + rescan. Block = 1024 (16 waves)
// covers 64 consecutive queries. Also zeroes acc + ticket for pass 3.
// ---------------------------------------------------------------------------
template <int SPL>
__global__ __launch_bounds__(1024) void nn_merge_rescan_kernel(
    const float* __restrict__ pw, const float* __restrict__ pp,
    const float* __restrict__ tw, const float* __restrict__ tp,
    const float* __restrict__ part_d, const unsigned char* __restrict__ part_t,
    int* __restrict__ idx_all, double* __restrict__ acc,
    unsigned int* __restrict__ ticket) {
  __shared__ float md[16][64];
  __shared__ int mg[16][64];
  __shared__ float sdq[64];
  __shared__ int sgq[64];

  if (blockIdx.x == 0 && threadIdx.x == 0) { *acc = 0.0; *ticket = 0u; }

  const int tid = threadIdx.x;
  const int wv = tid >> 6;          // wave id, 0..15
  const int lane = tid & 63;
  const int qid0 = blockIdx.x * 64;

  // --- Merge phase: coalesced plane loads, per-wave partial lexmin ---
  {
    float bd = INFINITY;
    int bg = 0x7fffffff;
    for (int s = wv; s < SPL; s += 16) {
      const size_t o = (size_t)s * (NZB * NPTS) + qid0 + lane;  // 64 consecutive
      const float d = part_d[o];
      const int g = part_t[o];
      if (d < bd || (d == bd && g < bg)) { bd = d; bg = g; }
    }
    md[wv][lane] = bd;
    mg[wv][lane] = bg;
  }
  __syncthreads();
  if (wv == 0) {                    // wave 0: final 16-way reduce per query
    float bd = md[0][lane];
    int bg = mg[0][lane];
    #pragma unroll
    for (int v = 1; v < 16; ++v) {
      const float d = md[v][lane];
      const int g = mg[v][lane];
      if (d < bd || (d == bd && g < bg)) { bd = d; bg = g; }
    }
    sdq[lane] = bd;
    sgq[lane] = bg;
  }
  __syncthreads();

  // --- Rescan phase: wave v -> queries v*4 .. v*4+3 ---
  const int zb = qid0 >> 13;        // uniform per block
  const int z = zb >> 2;
  const int b = zb & 3;
  const float* qa;
  const float* cb;
  pick_ab(z, pw, pp, tw, tp, &qa, &cb);
  const float* qb0 = qa + (size_t)b * NPTS * 3;
  const float* cbb = cb + (size_t)b * NPTS * 3;
  const int n0 = qid0 & (NPTS - 1);

  #pragma unroll
  for (int j = 0; j < 4; ++j) {
    const int lq = wv * 4 + j;
    const float best_d = sdq[lq];   // LDS broadcast
    const int best_g = sgq[lq];
    const float* q = qb0 + (size_t)(n0 + lq) * 3;   // wave-uniform 12B
    const float qx = -2.0f * q[0];
    const float qy = -2.0f * q[1];
    const float qz = -2.0f * q[2];
    const int m = best_g * SUBT + lane;             // contiguous across wave
    const float* c = cbb + (size_t)m * 3;
    const float bx = c[0], by = c[1], bz = c[2];
    const float b2 = fmaf(bx, bx, fmaf(by, by, bz * bz));
    const float dd = fmaf(qx, bx, fmaf(qy, by, fmaf(qz, bz, b2)));
    const unsigned long long hit = __ballot(dd == best_d);
    if (lane == 0)
      idx_all[qid0 + lq] = best_g * SUBT + (__ffsll((long long)hit) - 1);
  }
}

// ---------------------------------------------------------------------------
// Pass 3 (proven R9): loss (4 MSN terms split across blockIdx.y) + fused
// finalize. One acc-atomic per block; ordering via the atomic's RETURN VALUE
// before the ticket bump. Last of the 512 blocks writes out.
// loss = 0.25 * (sum of 4 squared-norm sums) / (B*N)
// ---------------------------------------------------------------------------
__device__ __forceinline__ float3 ld3(const float* __restrict__ p, int i) {
  const float* q = p + (size_t)i * 3;
  return make_float3(q[0], q[1], q[2]);
}

__device__ __forceinline__ float diff_nrm2(float3 a1, float3 a2, float3 b1, float3 b2) {
  const float x = (a1.x - a2.x) - (b1.x - b2.x);
  const float y = (a1.y - a2.y) - (b1.y - b2.y);
  const float z = (a1.z - a2.z) - (b1.z - b2.z);
  return fmaf(x, x, fmaf(y, y, z * z));
}

__global__ __launch_bounds__(256) void loss_final_kernel(
    const float* __restrict__ pw, const float* __restrict__ pp,
    const float* __restrict__ tw, const float* __restrict__ tp,
    const int* __restrict__ ipw, const int* __restrict__ itw,
    const int* __restrict__ ipp, const int* __restrict__ itp,
    const int* __restrict__ idx_all, double* __restrict__ acc,
    unsigned int* __restrict__ ticket, float* __restrict__ out) {
  __shared__ double sd[4];

  const int gid = blockIdx.x * 256 + threadIdx.x;  // [0, B*N)
  const int term = blockIdx.y;
  const int b = gid >> 13;
  const int n = gid & (NPTS - 1);
  const int base = b * NPTS;

  const float* PW = pw + (size_t)base * 3;
  const float* PP = pp + (size_t)base * 3;
  const float* TW = tw + (size_t)base * 3;
  const float* TP = tp + (size_t)base * 3;
  const int* I1P = idx_all + (0 * BATCH + b) * NPTS;  // NN pial for white (pred)
  const int* I2P = idx_all + (1 * BATCH + b) * NPTS;  // NN white for pial (pred)
  const int* I1T = idx_all + (2 * BATCH + b) * NPTS;  // NN pial for white (true)
  const int* I2T = idx_all + (3 * BATCH + b) * NPTS;  // NN white for pial (true)

  float sv;
  if (term == 0) {        // msn(yp_inner, yt_inner[i_pred_white])
    const int j = ipw[base + n];
    sv = diff_nrm2(ld3(PP, I1P[n]), ld3(PW, n), ld3(TP, I1T[j]), ld3(TW, j));
  } else if (term == 1) { // msn(yp_inner[i_true_white], yt_inner)
    const int k = itw[base + n];
    sv = diff_nrm2(ld3(PP, I1P[k]), ld3(PW, k), ld3(TP, I1T[n]), ld3(TW, n));
  } else if (term == 2) { // msn(yp_outer, yt_outer[i_pred_pial])
    const int j = ipp[base + n];
    sv = diff_nrm2(ld3(PP, n), ld3(PW, I2P[n]), ld3(TP, j), ld3(TW, I2T[j]));
  } else {                // msn(yp_outer[i_true_pial], yt_outer)
    const int k = itp[base + n];
    sv = diff_nrm2(ld3(PP, k), ld3(PW, I2P[k]), ld3(TP, n), ld3(TW, I2T[n]));
  }

  // Wave shuffle-reduce -> LDS -> single block sum.
  double ds = (double)sv;
  #pragma unroll
  for (int o = 32; o > 0; o >>= 1) ds += __shfl_down(ds, o, 64);
  if ((threadIdx.x & 63) == 0) sd[threadIdx.x >> 6] = ds;
  __syncthreads();

  if (threadIdx.x == 0) {
    const double bsum = sd[0] + sd[1] + sd[2] + sd[3];
    const double old = atomicAdd(acc, bsum);   // return forces completion
    // Data-dependency on 'old' orders the ticket bump after the acc add.
    const unsigned int inc = 1u + (unsigned int)(((unsigned long long)
                             __double_as_longlong(old)) & 0ull);
    const unsigned int total = gridDim.x * gridDim.y;   // 512
    const unsigned int t = atomicAdd(ticket, inc);
    if (t == total - 1u) {
      const double fin = atomicAdd(acc, 0.0);  // atomic read of the full sum
      out[0] = (float)(0.25 * fin / (double)BN);
    }
  }
}

// ---------------------------------------------------------------------------
template <int SPL>
static void run_pipeline(const float* pw, const float* pp, const float* tw,
                         const float* tp, const int* ipw, const int* itw,
                         const int* ipp, const int* itp, char* ws, float* out,
                         hipStream_t stream) {
  double* acc = (double*)ws;
  unsigned int* ticket = (unsigned int*)(ws + 8);
  int* idx_all = (int*)(ws + 64);
  float* part_d = (float*)(ws + 64 + (size_t)NZB * NPTS * 4);
  unsigned char* part_t =
      (unsigned char*)(ws + 64 + (size_t)NZB * NPTS * 4 +
                       (size_t)SPL * NZB * NPTS * 4);

  dim3 grid_nn(NPTS / QBLK, SPL, NZB);
  nn_partial_kernel<SPL><<<grid_nn, 256, 0, stream>>>(pw, pp, tw, tp, part_d,
                                                      part_t);
  nn_merge_rescan_kernel<SPL><<<(NZB * NPTS) / 64, 1024, 0, stream>>>(
      pw, pp, tw, tp, part_d, part_t, idx_all, acc, ticket);

  dim3 grid_loss(BN / 256, 4);
  loss_final_kernel<<<grid_loss, 256, 0, stream>>>(
      pw, pp, tw, tp, ipw, itw, ipp, itp, idx_all, acc, ticket, out);
}

extern "C" void kernel_launch(void* const* d_in, const int* in_sizes, int n_in,
                              void* d_out, int out_size, void* d_ws, size_t ws_size,
                              hipStream_t stream) {
  const float* pw = (const float*)d_in[0];
  const float* pp = (const float*)d_in[1];
  const float* tw = (const float*)d_in[2];
  const float* tp = (const float*)d_in[3];
  const int* ipw = (const int*)d_in[4];
  const int* itw = (const int*)d_in[5];
  const int* ipp = (const int*)d_in[6];
  const int* itp = (const int*)d_in[7];
  char* ws = (char*)d_ws;
  float* out = (float*)d_out;

  // Prefer SPL=16: same scan occupancy (4 blocks/CU resident), half the ws.
  const size_t base_need = 64 + (size_t)NZB * NPTS * 4;
  const size_t per_spl = (size_t)NZB * NPTS * 5;
  if (ws_size >= base_need + 16 * per_spl) {
    run_pipeline<16>(pw, pp, tw, tp, ipw, itw, ipp, itp, ws, out, stream);
  } else {
    run_pipeline<8>(pw, pp, tw, tp, ipw, itw, ipp, itp, ws, out, stream);
  }
}